// Round 1
// baseline (324.063 us; speedup 1.0000x reference)
//
#include <hip/hip_runtime.h>
#include <hip/hip_bf16.h>
#include <math.h>

// SparseMLP: W=8 experts, per w: out = gelu(X @ W1 + b1) @ W2 + b2
// X: (8, 2048, 2048) f32, W1: (8, 2048, 1024) f32, W2: (8, 1024, 2048) f32
// Round 1: bf16 MFMA, 128x128 tile (m97 structure), reg-staged conversion,
// pre-transposed B operands in ws. Padded LDS (stride 40 bf16 = 80B) so
// ds_read_b128 fragment loads are <=2-way bank aliased (free per m136).

typedef float f32x4 __attribute__((ext_vector_type(4)));
typedef short bf16x8 __attribute__((ext_vector_type(8)));
typedef short bf16x4 __attribute__((ext_vector_type(4)));
typedef unsigned short u16;

#define NW 8
#define MDIM 2048   // BHS*SEQ
#define HDIM 2048
#define FFN  1024

static __device__ __forceinline__ u16 f32_to_bf16_rn(float f) {
  union { float f; unsigned u; } v; v.f = f;
  unsigned r = v.u + 0x7FFF + ((v.u >> 16) & 1);
  return (u16)(r >> 16);
}

// in: (NW, R, C) f32  ->  out: (NW, C, R) bf16   (convert + transpose)
__global__ void convert_transpose_kernel(const float* __restrict__ in,
                                         u16* __restrict__ out, int R, int C) {
  __shared__ u16 tile[32][33];
  int w = blockIdx.z;
  int c0 = blockIdx.x * 32, r0 = blockIdx.y * 32;
  int tx = threadIdx.x, ty = threadIdx.y;  // 32 x 8
  const float* ip = in + (size_t)w * R * C;
  u16* op = out + (size_t)w * C * R;
#pragma unroll
  for (int j = 0; j < 4; ++j) {
    int r = r0 + ty + j * 8;
    tile[ty + j * 8][tx] = f32_to_bf16_rn(ip[(size_t)r * C + c0 + tx]);
  }
  __syncthreads();
#pragma unroll
  for (int j = 0; j < 4; ++j) {
    int c = c0 + ty + j * 8;
    op[(size_t)c * R + r0 + tx] = tile[tx][ty + j * 8];
  }
}

// C = op(A @ B^T + bias); A: (NW,M,K) f32 or bf16; Bt: (NW,N,K) bf16.
// 128x128 tile, BK=32, 4 waves in 2x2, each wave 64x64 (4x4 frags of 16x16x32).
template <bool A_F32, bool GELU, bool C_F32>
__global__ __launch_bounds__(256, 2) void mlp_gemm(
    const void* __restrict__ Aptr, const u16* __restrict__ Bt,
    const float* __restrict__ bias, void* __restrict__ Cptr,
    int M, int N, int K) {
  __shared__ u16 Als[128][40];
  __shared__ u16 Bls[128][40];
  int w = blockIdx.z;
  int n0 = blockIdx.x * 128, m0 = blockIdx.y * 128;
  int tid = threadIdx.x;
  int wid = tid >> 6, lane = tid & 63;
  int wr = wid >> 1, wc = wid & 1;
  int qa = lane >> 4, ra = lane & 15;

  const u16* btp = Bt + (size_t)w * N * K;
  const float* bp = bias + (size_t)w * N;

  f32x4 acc[4][4];
#pragma unroll
  for (int i = 0; i < 4; ++i)
#pragma unroll
    for (int j = 0; j < 4; ++j)
#pragma unroll
      for (int r = 0; r < 4; ++r) acc[i][j][r] = 0.0f;

  const int nK = K >> 5;
  for (int kt = 0; kt < nK; ++kt) {
    int k0 = kt << 5;
    __syncthreads();  // previous iter's frag reads done before overwrite
    if (A_F32) {
      const float* ap = (const float*)Aptr + (size_t)w * M * K;
      int c4 = (tid & 7) * 4;
#pragma unroll
      for (int it = 0; it < 4; ++it) {
        int r = (tid >> 3) + it * 32;
        f32x4 v = *(const f32x4*)(ap + (size_t)(m0 + r) * K + k0 + c4);
        bf16x4 pk;
        pk[0] = (short)f32_to_bf16_rn(v.x);
        pk[1] = (short)f32_to_bf16_rn(v.y);
        pk[2] = (short)f32_to_bf16_rn(v.z);
        pk[3] = (short)f32_to_bf16_rn(v.w);
        *(bf16x4*)&Als[r][c4] = pk;
      }
    } else {
      const u16* ap = (const u16*)Aptr + (size_t)w * M * K;
      int c8 = (tid & 3) * 8;
#pragma unroll
      for (int it = 0; it < 2; ++it) {
        int r = (tid >> 2) + it * 64;
        bf16x8 v = *(const bf16x8*)(ap + (size_t)(m0 + r) * K + k0 + c8);
        *(bf16x8*)&Als[r][c8] = v;
      }
    }
    {
      int c8 = (tid & 3) * 8;
#pragma unroll
      for (int it = 0; it < 2; ++it) {
        int r = (tid >> 2) + it * 64;
        bf16x8 v = *(const bf16x8*)(btp + (size_t)(n0 + r) * K + k0 + c8);
        *(bf16x8*)&Bls[r][c8] = v;
      }
    }
    __syncthreads();

    bf16x8 afr[4], bfr[4];
#pragma unroll
    for (int i = 0; i < 4; ++i)
      afr[i] = *(const bf16x8*)&Als[wr * 64 + i * 16 + ra][qa * 8];
#pragma unroll
    for (int j = 0; j < 4; ++j)
      bfr[j] = *(const bf16x8*)&Bls[wc * 64 + j * 16 + ra][qa * 8];
#pragma unroll
    for (int i = 0; i < 4; ++i)
#pragma unroll
      for (int j = 0; j < 4; ++j)
        acc[i][j] = __builtin_amdgcn_mfma_f32_16x16x32_bf16(afr[i], bfr[j],
                                                            acc[i][j], 0, 0, 0);
  }

  // epilogue: + bias, optional exact GELU, store
#pragma unroll
  for (int i = 0; i < 4; ++i) {
#pragma unroll
    for (int j = 0; j < 4; ++j) {
      int col = n0 + wc * 64 + j * 16 + ra;
      float bv = bp[col];
#pragma unroll
      for (int r = 0; r < 4; ++r) {
        int row = m0 + wr * 64 + i * 16 + qa * 4 + r;
        float v = acc[i][j][r] + bv;
        if (GELU) v = 0.5f * v * (1.0f + erff(v * 0.70710678118654752f));
        if (C_F32)
          ((float*)Cptr)[(size_t)w * M * N + (size_t)row * N + col] = v;
        else
          ((u16*)Cptr)[(size_t)w * M * N + (size_t)row * N + col] =
              f32_to_bf16_rn(v);
      }
    }
  }
}

__global__ void bias_out_kernel(const float* __restrict__ b2,
                                float* __restrict__ outb) {
  int i = blockIdx.x * 256 + threadIdx.x;
  if (i < NW * HDIM) outb[i] = b2[i];
}

extern "C" void kernel_launch(void* const* d_in, const int* in_sizes, int n_in,
                              void* d_out, int out_size, void* d_ws,
                              size_t ws_size, hipStream_t stream) {
  const float* hs = (const float*)d_in[0];  // (8,2,1024,2048)
  const float* w1 = (const float*)d_in[1];  // (8,2048,1024)
  const float* b1 = (const float*)d_in[2];  // (8,1,1024)
  const float* w2 = (const float*)d_in[3];  // (8,1024,2048)
  const float* b2 = (const float*)d_in[4];  // (8,2048)

  // ws layout (bf16): W1t (8,1024,2048) | W2t (8,2048,1024) | inter (8,2048,1024)
  u16* W1t = (u16*)d_ws;
  u16* W2t = W1t + (size_t)NW * FFN * HDIM;
  u16* inter = W2t + (size_t)NW * HDIM * FFN;

  dim3 tb(32, 8);
  // w1 (R=HDIM, C=FFN) -> W1t (FFN, HDIM)
  convert_transpose_kernel<<<dim3(FFN / 32, HDIM / 32, NW), tb, 0, stream>>>(
      w1, W1t, HDIM, FFN);
  // w2 (R=FFN, C=HDIM) -> W2t (HDIM, FFN)
  convert_transpose_kernel<<<dim3(HDIM / 32, FFN / 32, NW), tb, 0, stream>>>(
      w2, W2t, FFN, HDIM);

  // inter = gelu(X @ W1 + b1)  [bf16 out]
  mlp_gemm<true, true, false>
      <<<dim3(FFN / 128, MDIM / 128, NW), 256, 0, stream>>>(
          hs, W1t, b1, inter, MDIM, FFN, HDIM);
  // out = inter @ W2 + b2  [f32 out]
  mlp_gemm<false, false, true>
      <<<dim3(HDIM / 128, MDIM / 128, NW), 256, 0, stream>>>(
          inter, W2t, b2, d_out, MDIM, HDIM, FFN);

  // out_bias tail
  float* outb = (float*)d_out + (size_t)NW * MDIM * HDIM;
  bias_out_kernel<<<dim3((NW * HDIM + 255) / 256), 256, 0, stream>>>(b2, outb);
}

// Round 2
// 284.735 us; speedup vs baseline: 1.1381x; 1.1381x over previous
//
#include <hip/hip_runtime.h>
#include <hip/hip_bf16.h>
#include <math.h>

// SparseMLP: W=8 experts, per w: out = gelu(X @ W1 + b1) @ W2 + b2
// Round 2: m97 structure — both GEMM operands bf16, staged via
// global_load_lds dwordx4 into linear [128][32] LDS (wave-uniform chunk
// base + lane*16), 128x128 tile, BK=32, 4 waves 2x2, mfma_f32_16x16x32_bf16.
// X converted to bf16 in a prepass (kills in-loop cvt VALU + halves A bytes).

typedef float f32x4 __attribute__((ext_vector_type(4)));
typedef short bf16x8 __attribute__((ext_vector_type(8)));
typedef short bf16x4 __attribute__((ext_vector_type(4)));
typedef unsigned short u16;

#define NW 8
#define MDIM 2048   // BHS*SEQ
#define HDIM 2048
#define FFN  1024

static __device__ __forceinline__ u16 f32_to_bf16_rn(float f) {
  union { float f; unsigned u; } v; v.f = f;
  unsigned r = v.u + 0x7FFF + ((v.u >> 16) & 1);
  return (u16)(r >> 16);
}

static __device__ __forceinline__ void gload_lds16(const void* g, void* l) {
  __builtin_amdgcn_global_load_lds(
      (const __attribute__((address_space(1))) void*)g,
      (__attribute__((address_space(3))) void*)l, 16, 0, 0);
}

// X (NW*MDIM*HDIM f32) -> bf16, vectorized 4-wide
__global__ void convert_bf16_kernel(const float* __restrict__ in,
                                    u16* __restrict__ out) {
  size_t i = (size_t)blockIdx.x * blockDim.x + threadIdx.x;  // f32x4 index
  f32x4 v = ((const f32x4*)in)[i];
  bf16x4 p;
  p[0] = (short)f32_to_bf16_rn(v.x);
  p[1] = (short)f32_to_bf16_rn(v.y);
  p[2] = (short)f32_to_bf16_rn(v.z);
  p[3] = (short)f32_to_bf16_rn(v.w);
  ((bf16x4*)out)[i] = p;
}

// in: (NW, R, C) f32  ->  out: (NW, C, R) bf16 (convert + transpose), 64x64 tile
__global__ void convert_transpose_kernel(const float* __restrict__ in,
                                         u16* __restrict__ out, int R, int C) {
  __shared__ u16 tile[64][68];
  int w = blockIdx.z;
  int c0 = blockIdx.x * 64, r0 = blockIdx.y * 64;
  int t = threadIdx.x;                 // 256 threads
  const float* ip = in + (size_t)w * R * C;
  u16* op = out + (size_t)w * C * R;
  int tr = t >> 4;                     // 0..15
  int tc4 = (t & 15) * 4;              // 0..60
#pragma unroll
  for (int j = 0; j < 4; ++j) {
    int r = tr + j * 16;
    f32x4 v = *(const f32x4*)(ip + (size_t)(r0 + r) * C + c0 + tc4);
    tile[r][tc4 + 0] = f32_to_bf16_rn(v.x);
    tile[r][tc4 + 1] = f32_to_bf16_rn(v.y);
    tile[r][tc4 + 2] = f32_to_bf16_rn(v.z);
    tile[r][tc4 + 3] = f32_to_bf16_rn(v.w);
  }
  __syncthreads();
#pragma unroll
  for (int j = 0; j < 4; ++j) {
    int c = tr + j * 16;
    bf16x4 p;
    p[0] = (short)tile[tc4 + 0][c];
    p[1] = (short)tile[tc4 + 1][c];
    p[2] = (short)tile[tc4 + 2][c];
    p[3] = (short)tile[tc4 + 3][c];
    *(bf16x4*)(op + (size_t)(c0 + c) * R + r0 + tc4) = p;
  }
}

// C = op(A @ B^T + bias); A: (NW,M,K) bf16; Bt: (NW,N,K) bf16.
// 128x128 tile, BK=32, 4 waves 2x2, each wave 64x64 (4x4 frags of 16x16x32).
template <bool GELU, bool C_F32>
__global__ void mlp_gemm(const u16* __restrict__ A, const u16* __restrict__ Bt,
                         const float* __restrict__ bias, void* __restrict__ Cptr,
                         int M, int N, int K) {
  __shared__ u16 Als[128][32];   // linear: row = 64B -> chunk = 16 rows = 1024B
  __shared__ u16 Bls[128][32];
  int w = blockIdx.z;
  int n0 = blockIdx.x * 128, m0 = blockIdx.y * 128;
  int tid = threadIdx.x;
  int wid = tid >> 6, lane = tid & 63;
  int wr = wid >> 1, wc = wid & 1;
  int qa = lane >> 4, ra = lane & 15;

  const u16* ap = A + (size_t)w * M * K;
  const u16* btp = Bt + (size_t)w * N * K;
  const float* bp = bias + (size_t)w * N;

  int rowc = lane >> 2;            // row within 16-row chunk
  int sege = (lane & 3) * 8;       // elem offset within row (8 bf16 = 16B)

  f32x4 acc[4][4];
#pragma unroll
  for (int i = 0; i < 4; ++i)
#pragma unroll
    for (int j = 0; j < 4; ++j)
#pragma unroll
      for (int r = 0; r < 4; ++r) acc[i][j][r] = 0.0f;

  const int nK = K >> 5;
  for (int kt = 0; kt < nK; ++kt) {
    int k0 = kt << 5;
    __syncthreads();  // frag reads of prev iter done before overwrite
#pragma unroll
    for (int c = 0; c < 2; ++c) {
      int ch = wid * 2 + c;  // wave-uniform chunk id 0..7
      gload_lds16(ap + (size_t)(m0 + ch * 16 + rowc) * K + k0 + sege,
                  (char*)Als + ch * 1024);
      gload_lds16(btp + (size_t)(n0 + ch * 16 + rowc) * K + k0 + sege,
                  (char*)Bls + ch * 1024);
    }
    __syncthreads();  // compiler drains vmcnt before barrier

    bf16x8 afr[4], bfr[4];
#pragma unroll
    for (int i = 0; i < 4; ++i)
      afr[i] = *(const bf16x8*)&Als[wr * 64 + i * 16 + ra][qa * 8];
#pragma unroll
    for (int j = 0; j < 4; ++j)
      bfr[j] = *(const bf16x8*)&Bls[wc * 64 + j * 16 + ra][qa * 8];
#pragma unroll
    for (int i = 0; i < 4; ++i)
#pragma unroll
      for (int j = 0; j < 4; ++j)
        acc[i][j] = __builtin_amdgcn_mfma_f32_16x16x32_bf16(afr[i], bfr[j],
                                                            acc[i][j], 0, 0, 0);
  }

  // epilogue: + bias, optional exact GELU, store
#pragma unroll
  for (int i = 0; i < 4; ++i) {
#pragma unroll
    for (int j = 0; j < 4; ++j) {
      int col = n0 + wc * 64 + j * 16 + ra;
      float bv = bp[col];
#pragma unroll
      for (int r = 0; r < 4; ++r) {
        int row = m0 + wr * 64 + i * 16 + qa * 4 + r;
        float v = acc[i][j][r] + bv;
        if (GELU) v = 0.5f * v * (1.0f + erff(v * 0.70710678118654752f));
        if (C_F32)
          ((float*)Cptr)[(size_t)w * M * N + (size_t)row * N + col] = v;
        else
          ((u16*)Cptr)[(size_t)w * M * N + (size_t)row * N + col] =
              f32_to_bf16_rn(v);
      }
    }
  }
}

__global__ void bias_out_kernel(const float* __restrict__ b2,
                                float* __restrict__ outb) {
  int i = blockIdx.x * 256 + threadIdx.x;
  if (i < NW * HDIM) outb[i] = b2[i];
}

extern "C" void kernel_launch(void* const* d_in, const int* in_sizes, int n_in,
                              void* d_out, int out_size, void* d_ws,
                              size_t ws_size, hipStream_t stream) {
  const float* hs = (const float*)d_in[0];  // (8,2,1024,2048) f32
  const float* w1 = (const float*)d_in[1];  // (8,2048,1024) f32
  const float* b1 = (const float*)d_in[2];  // (8,1,1024) f32
  const float* w2 = (const float*)d_in[3];  // (8,1024,2048) f32
  const float* b2 = (const float*)d_in[4];  // (8,2048) f32

  // ws layout (u16): W1t (8,1024,2048) | W2t (8,2048,1024) | inter (8,2048,1024) | Xb (8,2048,2048)
  u16* W1t = (u16*)d_ws;
  u16* W2t = W1t + (size_t)NW * FFN * HDIM;
  u16* inter = W2t + (size_t)NW * HDIM * FFN;
  u16* XbWs = inter + (size_t)NW * MDIM * FFN;
  size_t need = ((size_t)NW * FFN * HDIM * 2 + (size_t)NW * MDIM * FFN +
                 (size_t)NW * MDIM * HDIM) * sizeof(u16);
  // fallback: stage X-bf16 in d_out's first 67 MB (GEMM1 consumes it before
  // GEMM2 overwrites d_out); deterministic either way
  u16* Xb = (ws_size >= need) ? XbWs : (u16*)d_out;

  // X -> bf16
  convert_bf16_kernel<<<dim3(NW * MDIM * HDIM / 4 / 256), 256, 0, stream>>>(hs, Xb);
  // w1 (R=HDIM, C=FFN) -> W1t (FFN, HDIM)
  convert_transpose_kernel<<<dim3(FFN / 64, HDIM / 64, NW), 256, 0, stream>>>(
      w1, W1t, HDIM, FFN);
  // w2 (R=FFN, C=HDIM) -> W2t (HDIM, FFN)
  convert_transpose_kernel<<<dim3(HDIM / 64, FFN / 64, NW), 256, 0, stream>>>(
      w2, W2t, FFN, HDIM);

  // inter = gelu(X @ W1 + b1)  [bf16 out]
  mlp_gemm<true, false><<<dim3(FFN / 128, MDIM / 128, NW), 256, 0, stream>>>(
      Xb, W1t, b1, inter, MDIM, FFN, HDIM);
  // out = inter @ W2 + b2  [f32 out]
  mlp_gemm<false, true><<<dim3(HDIM / 128, MDIM / 128, NW), 256, 0, stream>>>(
      inter, W2t, b2, d_out, MDIM, HDIM, FFN);

  // out_bias tail
  float* outb = (float*)d_out + (size_t)NW * MDIM * HDIM;
  bias_out_kernel<<<dim3((NW * HDIM + 255) / 256), 256, 0, stream>>>(b2, outb);
}

// Round 3
// 269.686 us; speedup vs baseline: 1.2016x; 1.0558x over previous
//
#include <hip/hip_runtime.h>
#include <hip/hip_bf16.h>
#include <math.h>

// SparseMLP: W=8 experts, per w: out = gelu(X @ W1 + b1) @ W2 + b2
// Round 3: phase-split GEMM (T2+T3+T4+T5). BM=128 BN=256 BK=64, 512 thr
// (8 waves 2Mx4N, wave tile 64x64), ring-of-3 LDS slots (48KB each = A16K+B32K).
// Counted vmcnt(6) per K-tile (never 0 in steady state), 2 phases/K-tile each
// {ds_read frags; stage 3 units; s_barrier; lgkmcnt(0); setprio(1); 16 MFMA;
// setprio(0); s_barrier}. LDS XOR-swizzle byte^=(row&7)<<4 (2-way = free) with
// inverse-swizzled global source for global_load_lds (linear dest, rule #21).

typedef float f32x4 __attribute__((ext_vector_type(4)));
typedef short bf16x8 __attribute__((ext_vector_type(8)));
typedef short bf16x4 __attribute__((ext_vector_type(4)));
typedef unsigned short u16;

#define NW 8
#define MDIM 2048   // BHS*SEQ
#define HDIM 2048
#define FFN  1024

static __device__ __forceinline__ u16 f32_to_bf16_rn(float f) {
  union { float f; unsigned u; } v; v.f = f;
  unsigned r = v.u + 0x7FFF + ((v.u >> 16) & 1);
  return (u16)(r >> 16);
}

static __device__ __forceinline__ void gload_lds16(const void* g, void* l) {
  __builtin_amdgcn_global_load_lds(
      (const __attribute__((address_space(1))) void*)g,
      (__attribute__((address_space(3))) void*)l, 16, 0, 0);
}

// X (NW*MDIM*HDIM f32) -> bf16, vectorized 4-wide
__global__ void convert_bf16_kernel(const float* __restrict__ in,
                                    u16* __restrict__ out) {
  size_t i = (size_t)blockIdx.x * blockDim.x + threadIdx.x;  // f32x4 index
  f32x4 v = ((const f32x4*)in)[i];
  bf16x4 p;
  p[0] = (short)f32_to_bf16_rn(v.x);
  p[1] = (short)f32_to_bf16_rn(v.y);
  p[2] = (short)f32_to_bf16_rn(v.z);
  p[3] = (short)f32_to_bf16_rn(v.w);
  ((bf16x4*)out)[i] = p;
}

// in: (NW, R, C) f32  ->  out: (NW, C, R) bf16 (convert + transpose), 64x64 tile
__global__ void convert_transpose_kernel(const float* __restrict__ in,
                                         u16* __restrict__ out, int R, int C) {
  __shared__ u16 tile[64][68];
  int w = blockIdx.z;
  int c0 = blockIdx.x * 64, r0 = blockIdx.y * 64;
  int t = threadIdx.x;  // 256 threads
  const float* ip = in + (size_t)w * R * C;
  u16* op = out + (size_t)w * C * R;
  int tr = t >> 4;       // 0..15
  int tc4 = (t & 15) * 4;
#pragma unroll
  for (int j = 0; j < 4; ++j) {
    int r = tr + j * 16;
    f32x4 v = *(const f32x4*)(ip + (size_t)(r0 + r) * C + c0 + tc4);
    tile[r][tc4 + 0] = f32_to_bf16_rn(v.x);
    tile[r][tc4 + 1] = f32_to_bf16_rn(v.y);
    tile[r][tc4 + 2] = f32_to_bf16_rn(v.z);
    tile[r][tc4 + 3] = f32_to_bf16_rn(v.w);
  }
  __syncthreads();
#pragma unroll
  for (int j = 0; j < 4; ++j) {
    int c = tr + j * 16;
    bf16x4 p;
    p[0] = (short)tile[tc4 + 0][c];
    p[1] = (short)tile[tc4 + 1][c];
    p[2] = (short)tile[tc4 + 2][c];
    p[3] = (short)tile[tc4 + 3][c];
    *(bf16x4*)(op + (size_t)(c0 + c) * R + r0 + tc4) = p;
  }
}

// ring-3 slot layout (48 KB): A [128 rows][128B] @ +0, B [256 rows][128B] @ +16384
#define SLOT_BYTES 49152
#define STAGE_A(pb, t, a)                                              \
  gload_lds16(gA + (size_t)(a) * 64 * 2 * K + (size_t)(t) * 128,       \
              (pb) + (a) * 8192 + tid * 16)
#define STAGE_B(pb, t, b)                                              \
  gload_lds16(gB + (size_t)(b) * 64 * 2 * K + (size_t)(t) * 128,       \
              (pb) + 16384 + (b) * 8192 + tid * 16)

template <bool GELU, bool C_F32>
__global__ __launch_bounds__(512, 2) void mlp_gemm(
    const u16* __restrict__ A, const u16* __restrict__ Bt,
    const float* __restrict__ bias, void* __restrict__ Cptr,
    int M, int N, int K) {
  __shared__ __align__(16) char lds[3 * SLOT_BYTES];

  const int w = blockIdx.z;
  const int n0 = blockIdx.x * 256, m0 = blockIdx.y * 128;
  const int tid = threadIdx.x;
  const int wid = tid >> 6, lane = tid & 63;
  const int wr = wid >> 2, wc = wid & 3;       // 2 M-waves x 4 N-waves
  const int qa = lane >> 4, ra = lane & 15;

  const u16* ap = A + (size_t)w * M * K;
  const u16* btp = Bt + (size_t)w * N * K;
  const float* bp = bias + (size_t)w * N;

  // staging: thread covers row r8 = tid>>3 (of each 64-row unit), 16B chunk
  // (tid&7); global col pre-swizzled so linear LDS dest yields swizzled layout
  const int r8 = tid >> 3;
  const int csw = ((tid & 7) * 16) ^ ((r8 & 7) << 4);
  const char* gA = (const char*)(ap + (size_t)(m0 + r8) * K) + csw;
  const char* gB = (const char*)(btp + (size_t)(n0 + r8) * K) + csw;

  // frag-read swizzled column base (row&7 == ra&7 for all frag rows)
  const int swk0 = (qa * 16) ^ ((ra & 7) << 4);

  f32x4 acc[4][4];
#pragma unroll
  for (int i = 0; i < 4; ++i)
#pragma unroll
    for (int j = 0; j < 4; ++j)
#pragma unroll
      for (int r = 0; r < 4; ++r) acc[i][j][r] = 0.0f;

  const int NT = K >> 6;

  // prologue: stage tiles 0 (slot 0) and 1 (slot 1); 12 loads/thread
  {
    char* s0 = lds;
    char* s1 = lds + SLOT_BYTES;
    STAGE_A(s0, 0, 0); STAGE_A(s0, 0, 1);
    STAGE_B(s0, 0, 0); STAGE_B(s0, 0, 1); STAGE_B(s0, 0, 2); STAGE_B(s0, 0, 3);
    STAGE_A(s1, 1, 0); STAGE_A(s1, 1, 1);
    STAGE_B(s1, 1, 0); STAGE_B(s1, 1, 1); STAGE_B(s1, 1, 2); STAGE_B(s1, 1, 3);
  }
  asm volatile("s_waitcnt vmcnt(6)" ::: "memory");  // tile 0 landed
  __builtin_amdgcn_sched_barrier(0);
  __builtin_amdgcn_s_barrier();

  int slot = 0;
  for (int t = 0; t < NT; ++t) {
    char* sb = lds + slot * SLOT_BYTES;
    int s2 = slot + 2; if (s2 >= 3) s2 -= 3;   // slot of tile t-1: dead
    char* pb = lds + s2 * SLOT_BYTES;
    const bool pf = (t + 2) < NT;

    // ---------- phase A: C-quadrant i=0,1 ----------
    bf16x8 afr[2][2], bfr[4][2];
#pragma unroll
    for (int i = 0; i < 2; ++i)
#pragma unroll
      for (int kk = 0; kk < 2; ++kk)
        afr[i][kk] = *(const bf16x8*)(sb + (wr * 64 + i * 16 + ra) * 128 +
                                      (swk0 ^ (kk << 6)));
#pragma unroll
    for (int j = 0; j < 4; ++j)
#pragma unroll
      for (int kk = 0; kk < 2; ++kk)
        bfr[j][kk] = *(const bf16x8*)(sb + 16384 +
                                      (wc * 64 + j * 16 + ra) * 128 +
                                      (swk0 ^ (kk << 6)));
    if (pf) { STAGE_A(pb, t + 2, 0); STAGE_A(pb, t + 2, 1); STAGE_B(pb, t + 2, 0); }
    __builtin_amdgcn_s_barrier();
    asm volatile("s_waitcnt lgkmcnt(0)" ::: "memory");
    __builtin_amdgcn_sched_barrier(0);
    __builtin_amdgcn_s_setprio(1);
#pragma unroll
    for (int i = 0; i < 2; ++i)
#pragma unroll
      for (int j = 0; j < 4; ++j)
#pragma unroll
        for (int kk = 0; kk < 2; ++kk)
          acc[i][j] = __builtin_amdgcn_mfma_f32_16x16x32_bf16(
              afr[i][kk], bfr[j][kk], acc[i][j], 0, 0, 0);
    __builtin_amdgcn_s_setprio(0);
    __builtin_amdgcn_s_barrier();

    // ---------- phase B: C-quadrant i=2,3 ----------
    bf16x8 afr2[2][2];
#pragma unroll
    for (int i = 0; i < 2; ++i)
#pragma unroll
      for (int kk = 0; kk < 2; ++kk)
        afr2[i][kk] = *(const bf16x8*)(sb + (wr * 64 + (2 + i) * 16 + ra) * 128 +
                                       (swk0 ^ (kk << 6)));
    if (pf) { STAGE_B(pb, t + 2, 1); STAGE_B(pb, t + 2, 2); STAGE_B(pb, t + 2, 3); }
    __builtin_amdgcn_s_barrier();
    asm volatile("s_waitcnt lgkmcnt(0)" ::: "memory");
    __builtin_amdgcn_sched_barrier(0);
    __builtin_amdgcn_s_setprio(1);
#pragma unroll
    for (int i = 0; i < 2; ++i)
#pragma unroll
      for (int j = 0; j < 4; ++j)
#pragma unroll
        for (int kk = 0; kk < 2; ++kk)
          acc[2 + i][j] = __builtin_amdgcn_mfma_f32_16x16x32_bf16(
              afr2[i][kk], bfr[j][kk], acc[2 + i][j], 0, 0, 0);
    __builtin_amdgcn_s_setprio(0);
    // counted vmcnt: keep tile t+2's 6 loads in flight; drain tile t+1
    if (t < NT - 2)
      asm volatile("s_waitcnt vmcnt(6)" ::: "memory");
    else
      asm volatile("s_waitcnt vmcnt(0)" ::: "memory");
    __builtin_amdgcn_sched_barrier(0);
    __builtin_amdgcn_s_barrier();

    slot = slot + 1; if (slot == 3) slot = 0;
  }

  // epilogue: + bias, optional exact GELU, store
#pragma unroll
  for (int i = 0; i < 4; ++i) {
#pragma unroll
    for (int j = 0; j < 4; ++j) {
      int col = n0 + wc * 64 + j * 16 + ra;
      float bv = bp[col];
#pragma unroll
      for (int r = 0; r < 4; ++r) {
        int row = m0 + wr * 64 + i * 16 + qa * 4 + r;
        float v = acc[i][j][r] + bv;
        if (GELU) v = 0.5f * v * (1.0f + erff(v * 0.70710678118654752f));
        if (C_F32)
          ((float*)Cptr)[(size_t)w * M * N + (size_t)row * N + col] = v;
        else
          ((u16*)Cptr)[(size_t)w * M * N + (size_t)row * N + col] =
              f32_to_bf16_rn(v);
      }
    }
  }
}

__global__ void bias_out_kernel(const float* __restrict__ b2,
                                float* __restrict__ outb) {
  int i = blockIdx.x * 256 + threadIdx.x;
  if (i < NW * HDIM) outb[i] = b2[i];
}

extern "C" void kernel_launch(void* const* d_in, const int* in_sizes, int n_in,
                              void* d_out, int out_size, void* d_ws,
                              size_t ws_size, hipStream_t stream) {
  const float* hs = (const float*)d_in[0];  // (8,2,1024,2048) f32
  const float* w1 = (const float*)d_in[1];  // (8,2048,1024) f32
  const float* b1 = (const float*)d_in[2];  // (8,1,1024) f32
  const float* w2 = (const float*)d_in[3];  // (8,1024,2048) f32
  const float* b2 = (const float*)d_in[4];  // (8,2048) f32

  // ws (u16): W1t (8,1024,2048) | W2t (8,2048,1024) | inter (8,2048,1024) | Xb (8,2048,2048)
  u16* W1t = (u16*)d_ws;
  u16* W2t = W1t + (size_t)NW * FFN * HDIM;
  u16* inter = W2t + (size_t)NW * HDIM * FFN;
  u16* XbWs = inter + (size_t)NW * MDIM * FFN;
  size_t need = ((size_t)NW * FFN * HDIM * 2 + (size_t)NW * MDIM * FFN +
                 (size_t)NW * MDIM * HDIM) * sizeof(u16);
  u16* Xb = (ws_size >= need) ? XbWs : (u16*)d_out;

  convert_bf16_kernel<<<dim3(NW * MDIM * HDIM / 4 / 256), 256, 0, stream>>>(hs, Xb);
  convert_transpose_kernel<<<dim3(FFN / 64, HDIM / 64, NW), 256, 0, stream>>>(
      w1, W1t, HDIM, FFN);
  convert_transpose_kernel<<<dim3(HDIM / 64, FFN / 64, NW), 256, 0, stream>>>(
      w2, W2t, FFN, HDIM);

  // inter = gelu(X @ W1 + b1)  [bf16 out]  M=2048 N=1024 K=2048
  mlp_gemm<true, false><<<dim3(FFN / 256, MDIM / 128, NW), 512, 0, stream>>>(
      Xb, W1t, b1, inter, MDIM, FFN, HDIM);
  // out = inter @ W2 + b2  [f32 out]  M=2048 N=2048 K=1024
  mlp_gemm<false, true><<<dim3(HDIM / 256, MDIM / 128, NW), 512, 0, stream>>>(
      inter, W2t, b2, d_out, MDIM, HDIM, FFN);

  float* outb = (float*)d_out + (size_t)NW * MDIM * HDIM;
  bias_out_kernel<<<dim3((NW * HDIM + 255) / 256), 256, 0, stream>>>(b2, outb);
}

// Round 4
// 245.146 us; speedup vs baseline: 1.3219x; 1.1001x over previous
//
#include <hip/hip_runtime.h>
#include <hip/hip_bf16.h>
#include <math.h>

// SparseMLP: W=8 experts, per w: out = gelu(X @ W1 + b1) @ W2 + b2
// Round 4: full m201 geometry. BM=BN=256, BK=64, 512 thr (8 waves 2Mx4N,
// wave tile 128x64), LDS 128KB = 2 K-tile dbuf x 4 half-tile regions (16KB).
// 8 phases / iteration (2 K-tiles): each phase {ds_read frags; stage <=2
// half-tiles; s_barrier; lgkmcnt(0); setprio(1); 16 MFMA; setprio(0);
// s_barrier}. Counted vmcnt(4) only at phases 4/8. Region-death schedule:
// B halves fully read in phase 1 (held in regs), A halves die at phase 4:
//   ph1: stage A0(t+1)   ph2: A1(t+1), B0(t+2)   ph3: B1(t+2)   ph4: vm(4)
//   ph5: A0(t+2)         ph6: A1(t+2), B0(t+3)   ph7: B1(t+3)   ph8: vm(4)
// XOR-swizzle byte^=(row&7)<<4 via inverse-swizzled global source (rule #21).
// Expert pinned to XCD: expert = bid%8 (one 4MB weight panel per XCD L2).

typedef float f32x4 __attribute__((ext_vector_type(4)));
typedef short bf16x8 __attribute__((ext_vector_type(8)));
typedef short bf16x4 __attribute__((ext_vector_type(4)));
typedef unsigned short u16;

#define NW 8
#define MDIM 2048   // BHS*SEQ
#define HDIM 2048
#define FFN  1024

static __device__ __forceinline__ u16 f32_to_bf16_rn(float f) {
  union { float f; unsigned u; } v; v.f = f;
  unsigned r = v.u + 0x7FFF + ((v.u >> 16) & 1);
  return (u16)(r >> 16);
}

static __device__ __forceinline__ void gload_lds16(const void* g, void* l) {
  __builtin_amdgcn_global_load_lds(
      (const __attribute__((address_space(1))) void*)g,
      (__attribute__((address_space(3))) void*)l, 16, 0, 0);
}

// X (NW*MDIM*HDIM f32) -> bf16, vectorized 4-wide
__global__ void convert_bf16_kernel(const float* __restrict__ in,
                                    u16* __restrict__ out) {
  size_t i = (size_t)blockIdx.x * blockDim.x + threadIdx.x;  // f32x4 index
  f32x4 v = ((const f32x4*)in)[i];
  bf16x4 p;
  p[0] = (short)f32_to_bf16_rn(v.x);
  p[1] = (short)f32_to_bf16_rn(v.y);
  p[2] = (short)f32_to_bf16_rn(v.z);
  p[3] = (short)f32_to_bf16_rn(v.w);
  ((bf16x4*)out)[i] = p;
}

// in: (NW, R, C) f32  ->  out: (NW, C, R) bf16 (convert + transpose), 64x64 tile
__global__ void convert_transpose_kernel(const float* __restrict__ in,
                                         u16* __restrict__ out, int R, int C) {
  __shared__ u16 tile[64][68];
  int w = blockIdx.z;
  int c0 = blockIdx.x * 64, r0 = blockIdx.y * 64;
  int t = threadIdx.x;  // 256 threads
  const float* ip = in + (size_t)w * R * C;
  u16* op = out + (size_t)w * C * R;
  int tr = t >> 4;       // 0..15
  int tc4 = (t & 15) * 4;
#pragma unroll
  for (int j = 0; j < 4; ++j) {
    int r = tr + j * 16;
    f32x4 v = *(const f32x4*)(ip + (size_t)(r0 + r) * C + c0 + tc4);
    tile[r][tc4 + 0] = f32_to_bf16_rn(v.x);
    tile[r][tc4 + 1] = f32_to_bf16_rn(v.y);
    tile[r][tc4 + 2] = f32_to_bf16_rn(v.z);
    tile[r][tc4 + 3] = f32_to_bf16_rn(v.w);
  }
  __syncthreads();
#pragma unroll
  for (int j = 0; j < 4; ++j) {
    int c = tr + j * 16;
    bf16x4 p;
    p[0] = (short)tile[tc4 + 0][c];
    p[1] = (short)tile[tc4 + 1][c];
    p[2] = (short)tile[tc4 + 2][c];
    p[3] = (short)tile[tc4 + 3][c];
    *(bf16x4*)(op + (size_t)(c0 + c) * R + r0 + tc4) = p;
  }
}

// LDS layout per K-tile buffer (64KB): A0 @0, A1 @16384, B0 @32768, B1 @49152
// Each half-region: [128 rows][128B], rows linear, bytes col-swizzled.
#define STAGE_AH(dst, tt, h)                                                  \
  do {                                                                        \
    gload_lds16(gA + (size_t)(h) * 128 * rowK + (size_t)(tt) * 128,           \
                (dst) + (h) * 16384 + tid * 16);                              \
    gload_lds16(gA + ((size_t)(h) * 128 + 64) * rowK + (size_t)(tt) * 128,    \
                (dst) + (h) * 16384 + 8192 + tid * 16);                       \
  } while (0)
#define STAGE_BH(dst, tt, h)                                                  \
  do {                                                                        \
    gload_lds16(gB + (size_t)(h) * 128 * rowK + (size_t)(tt) * 128,           \
                (dst) + 32768 + (h) * 16384 + tid * 16);                      \
    gload_lds16(gB + ((size_t)(h) * 128 + 64) * rowK + (size_t)(tt) * 128,    \
                (dst) + 32768 + (h) * 16384 + 8192 + tid * 16);               \
  } while (0)

// One phase: quadrant q (m-frags 2q,2q+1) of the K-tile in SB.
// first: also load all 8 B-frags (held in regs across the 4 phases).
#define DO_PHASE(SB, q, first, STAGES, VMCODE)                                \
  {                                                                           \
    if (first) {                                                              \
      _Pragma("unroll") for (int jj = 0; jj < 4; ++jj)                        \
          _Pragma("unroll") for (int kk = 0; kk < 2; ++kk)                    \
              bfr[jj][kk] = *(const bf16x8*)((SB) + Boff +                    \
                  (brow + jj * 16 + ra) * 128 + (colsw ^ (kk << 6)));         \
    }                                                                         \
    _Pragma("unroll") for (int ii = 0; ii < 2; ++ii)                          \
        _Pragma("unroll") for (int kk = 0; kk < 2; ++kk)                      \
            afr[ii][kk] = *(const bf16x8*)((SB) + Aoff +                      \
                ((q)*32 + ii * 16 + ra) * 128 + (colsw ^ (kk << 6)));         \
    STAGES;                                                                   \
    __builtin_amdgcn_s_barrier();                                             \
    asm volatile("s_waitcnt lgkmcnt(0)" ::: "memory");                        \
    __builtin_amdgcn_sched_barrier(0);                                        \
    __builtin_amdgcn_s_setprio(1);                                            \
    _Pragma("unroll") for (int ii = 0; ii < 2; ++ii)                          \
        _Pragma("unroll") for (int jj = 0; jj < 4; ++jj)                      \
            _Pragma("unroll") for (int kk = 0; kk < 2; ++kk)                  \
                acc[(q)*2 + ii][jj] =                                         \
                    __builtin_amdgcn_mfma_f32_16x16x32_bf16(                  \
                        afr[ii][kk], bfr[jj][kk], acc[(q)*2 + ii][jj],        \
                        0, 0, 0);                                             \
    __builtin_amdgcn_s_setprio(0);                                            \
    VMCODE;                                                                   \
    __builtin_amdgcn_s_barrier();                                             \
  }

// C = op(A @ B^T + bias); A: (NW,M,K) bf16; Bt: (NW,N,K) bf16.
template <bool GELU, bool C_F32>
__global__ __launch_bounds__(512, 2) void mlp_gemm(
    const u16* __restrict__ A, const u16* __restrict__ Bt,
    const float* __restrict__ bias, void* __restrict__ Cptr,
    int M, int N, int K, int nN) {
  __shared__ __align__(16) char lds[131072];
  char* cur = lds;            // even K-tiles
  char* nxt = lds + 65536;    // odd K-tiles

  const int bid = blockIdx.x;
  const int w = bid & 7;            // expert -> pinned to XCD bid%8
  const int jb = bid >> 3;
  const int m0 = (jb / nN) * 256;
  const int n0 = (jb % nN) * 256;

  const int tid = threadIdx.x;
  const int wid = tid >> 6, lane = tid & 63;
  const int wr = wid >> 2, wc = wid & 3;   // 2 M-waves x 4 N-waves
  const int qa = lane >> 4, ra = lane & 15;

  const u16* ap = A + (size_t)w * M * K;
  const u16* btp = Bt + (size_t)w * N * K;
  const float* bp = bias + (size_t)w * N;

  const size_t rowK = (size_t)K * 2;       // bytes per K-row
  const int r8 = tid >> 3;                 // 0..63
  const int csw = ((tid & 7) * 16) ^ ((r8 & 7) << 4);
  const char* gA = (const char*)ap + (size_t)(m0 + r8) * rowK + csw;
  const char* gB = (const char*)btp + (size_t)(n0 + r8) * rowK + csw;

  // fragment-read constants
  const int colsw = (qa * 16) ^ ((ra & 7) << 4);
  const int Aoff = wr * 16384;             // wave's A half-region
  const int Boff = 32768 + (wc >> 1) * 16384;
  const int brow = (wc & 1) * 64;

  f32x4 acc[8][4];
#pragma unroll
  for (int i = 0; i < 8; ++i)
#pragma unroll
    for (int j = 0; j < 4; ++j)
#pragma unroll
      for (int r = 0; r < 4; ++r) acc[i][j][r] = 0.0f;

  const int NT = K >> 6;       // 64-wide K-tiles (GEMM1: 32, GEMM2: 16)
  const int nIter = NT >> 1;

  // prologue: tile0 (cur) fully + tile1 (nxt) B-halves; 12 loads/thread
  STAGE_BH(cur, 0, 0); STAGE_BH(cur, 0, 1);
  STAGE_AH(cur, 0, 0); STAGE_AH(cur, 0, 1);
  STAGE_BH(nxt, 1, 0); STAGE_BH(nxt, 1, 1);
  asm volatile("s_waitcnt vmcnt(4)" ::: "memory");  // tile0 landed; B(1) fly
  __builtin_amdgcn_sched_barrier(0);
  __builtin_amdgcn_s_barrier();

  bf16x8 bfr[4][2], afr[2][2];
  for (int it = 0; it < nIter; ++it) {
    const int t = it * 2;
    const bool s2 = (t + 2) < NT, s3 = (t + 3) < NT;

    // ---- K-tile t (cur) ----
    DO_PHASE(cur, 0, 1, { STAGE_AH(nxt, t + 1, 0); }, {});
    DO_PHASE(cur, 1, 0,
             { STAGE_AH(nxt, t + 1, 1); if (s2) STAGE_BH(cur, t + 2, 0); }, {});
    DO_PHASE(cur, 2, 0, { if (s2) STAGE_BH(cur, t + 2, 1); }, {});
    DO_PHASE(cur, 3, 0, {}, {
      if (s2) asm volatile("s_waitcnt vmcnt(4)" ::: "memory");
      else    asm volatile("s_waitcnt vmcnt(0)" ::: "memory");
      __builtin_amdgcn_sched_barrier(0);
    });
    // ---- K-tile t+1 (nxt) ----
    DO_PHASE(nxt, 0, 1, { if (s2) STAGE_AH(cur, t + 2, 0); }, {});
    DO_PHASE(nxt, 1, 0,
             { if (s2) STAGE_AH(cur, t + 2, 1); if (s3) STAGE_BH(nxt, t + 3, 0); }, {});
    DO_PHASE(nxt, 2, 0, { if (s3) STAGE_BH(nxt, t + 3, 1); }, {});
    DO_PHASE(nxt, 3, 0, {}, {
      if (s3) asm volatile("s_waitcnt vmcnt(4)" ::: "memory");
      else    asm volatile("s_waitcnt vmcnt(0)" ::: "memory");
      __builtin_amdgcn_sched_barrier(0);
    });
  }

  // epilogue: + bias, optional exact GELU, store
#pragma unroll
  for (int i = 0; i < 8; ++i) {
#pragma unroll
    for (int j = 0; j < 4; ++j) {
      int col = n0 + wc * 64 + j * 16 + ra;
      float bv = bp[col];
#pragma unroll
      for (int r = 0; r < 4; ++r) {
        int row = m0 + wr * 128 + i * 16 + qa * 4 + r;
        float v = acc[i][j][r] + bv;
        if (GELU) v = 0.5f * v * (1.0f + erff(v * 0.70710678118654752f));
        if (C_F32)
          ((float*)Cptr)[(size_t)w * M * N + (size_t)row * N + col] = v;
        else
          ((u16*)Cptr)[(size_t)w * M * N + (size_t)row * N + col] =
              f32_to_bf16_rn(v);
      }
    }
  }
}

__global__ void bias_out_kernel(const float* __restrict__ b2,
                                float* __restrict__ outb) {
  int i = blockIdx.x * 256 + threadIdx.x;
  if (i < NW * HDIM) outb[i] = b2[i];
}

extern "C" void kernel_launch(void* const* d_in, const int* in_sizes, int n_in,
                              void* d_out, int out_size, void* d_ws,
                              size_t ws_size, hipStream_t stream) {
  const float* hs = (const float*)d_in[0];  // (8,2,1024,2048) f32
  const float* w1 = (const float*)d_in[1];  // (8,2048,1024) f32
  const float* b1 = (const float*)d_in[2];  // (8,1,1024) f32
  const float* w2 = (const float*)d_in[3];  // (8,1024,2048) f32
  const float* b2 = (const float*)d_in[4];  // (8,2048) f32

  // ws (u16): W1t (8,1024,2048) | W2t (8,2048,1024) | inter (8,2048,1024) | Xb (8,2048,2048)
  u16* W1t = (u16*)d_ws;
  u16* W2t = W1t + (size_t)NW * FFN * HDIM;
  u16* inter = W2t + (size_t)NW * HDIM * FFN;
  u16* XbWs = inter + (size_t)NW * MDIM * FFN;
  size_t need = ((size_t)NW * FFN * HDIM * 2 + (size_t)NW * MDIM * FFN +
                 (size_t)NW * MDIM * HDIM) * sizeof(u16);
  u16* Xb = (ws_size >= need) ? XbWs : (u16*)d_out;

  convert_bf16_kernel<<<dim3(NW * MDIM * HDIM / 4 / 256), 256, 0, stream>>>(hs, Xb);
  convert_transpose_kernel<<<dim3(FFN / 64, HDIM / 64, NW), 256, 0, stream>>>(
      w1, W1t, HDIM, FFN);
  convert_transpose_kernel<<<dim3(HDIM / 64, FFN / 64, NW), 256, 0, stream>>>(
      w2, W2t, FFN, HDIM);

  // inter = gelu(X @ W1 + b1)  [bf16]  M=2048 N=1024 K=2048 -> 256 blocks
  mlp_gemm<true, false><<<dim3(NW * (MDIM / 256) * (FFN / 256)), 512, 0, stream>>>(
      Xb, W1t, b1, inter, MDIM, FFN, HDIM, FFN / 256);
  // out = inter @ W2 + b2  [f32]  M=2048 N=2048 K=1024 -> 512 blocks
  mlp_gemm<false, true><<<dim3(NW * (MDIM / 256) * (HDIM / 256)), 512, 0, stream>>>(
      inter, W2t, b2, d_out, MDIM, HDIM, FFN, HDIM / 256);

  float* outb = (float*)d_out + (size_t)NW * MDIM * HDIM;
  bias_out_kernel<<<dim3((NW * HDIM + 255) / 256), 256, 0, stream>>>(b2, outb);
}